// Round 4
// baseline (508.553 us; speedup 1.0000x reference)
//
#include <hip/hip_runtime.h>

// HyperConnections fused kernel, MI355X (gfx950). ALL I/O float32.
// Shapes: h (8192, 4, 2048), h_o (8192, 2048), out (8192, 4, 2048).
//
// V4: wave-per-position, ZERO barriers (convoy-breaker, take 2).
//  V3 post-mortem: the HIP compiler emits s_waitcnt vmcnt(0) before every
//  s_barrier, so the 2 __syncthreads per position force-drain ALL in-flight
//  loads (including cross-position prefetch) -> per-position progress gated
//  by a full memory round-trip chip-wide -> 2.4-2.6 TB/s for V1/V2/V3 alike.
//  V4 removes every barrier: one wave owns one full position (64 lanes x 32 d).
//  The 28-value reduction is wave-internal: DPP row_shr/bcast to lane 63,
//  then v_readlane -> SGPR broadcast. No LDS, no DS ops, no syncthreads.
//  h is streamed twice (partials pass + output pass); the second read is
//  L1/L2-hot so HBM traffic is unchanged. Waves are fully independent ->
//  loads stay in flight continuously; only counted vmcnt waits remain.

#define NDIM   2048
#define NRATE  4
#define DSCALE 0.01f
#define LEPS   1e-5f

typedef float vfloat4 __attribute__((ext_vector_type(4)));

// ws float layout:
//   [0..9]            GA[4]=sum(g*A_k), BA[4]=sum(b*A_k), GB=sum(g*Bfn), BB=sum(b*Bfn)
//   [16 .. 16+8192)   pk4[d] = {A[d,1..4]}  (float4, 16B aligned)
#define WS_PK4 16

template <int C>
__device__ __forceinline__ float dppmv(float x) {
    return __builtin_bit_cast(float,
        __builtin_amdgcn_update_dpp(0, __builtin_bit_cast(int, x), C, 0xF, 0xF, true));
}

// Wave64 sum via DPP; result valid in lane 63.
__device__ __forceinline__ float wsum(float x) {
    x += dppmv<0x111>(x);   // row_shr:1
    x += dppmv<0x112>(x);   // row_shr:2
    x += dppmv<0x114>(x);   // row_shr:4
    x += dppmv<0x118>(x);   // row_shr:8
    x += dppmv<0x142>(x);   // row_bcast:15
    x += dppmv<0x143>(x);   // row_bcast:31
    return x;
}

// Broadcast lane 63's value to all lanes via SGPR (no DS traffic).
__device__ __forceinline__ float bcast63(float x) {
    return __builtin_bit_cast(float,
        __builtin_amdgcn_readlane(__builtin_bit_cast(int, x), 63));
}

__global__ __launch_bounds__(256) void hc_prep(
    const float* __restrict__ g_, const float* __restrict__ b_,
    const float* __restrict__ Afn, const float* __restrict__ Bfn,
    float* __restrict__ ws)
{
    __shared__ float s_red[4][10];
    const int t = threadIdx.x;
    const int lane = t & 63, wave = t >> 6;
    float acc[10];
    #pragma unroll
    for (int v = 0; v < 10; v++) acc[v] = 0.f;
    #pragma unroll
    for (int i = 0; i < 8; i++) {
        const int d = t * 8 + i;
        const float g  = g_[d];
        const float b  = b_[d];
        const float db = Bfn[d];
        const float a1 = Afn[d*5+1], a2 = Afn[d*5+2], a3 = Afn[d*5+3], a4 = Afn[d*5+4];
        *(float4*)(ws + WS_PK4 + 4*d) = make_float4(a1, a2, a3, a4);
        acc[0] = fmaf(g, a1, acc[0]); acc[1] = fmaf(g, a2, acc[1]);
        acc[2] = fmaf(g, a3, acc[2]); acc[3] = fmaf(g, a4, acc[3]);
        acc[4] = fmaf(b, a1, acc[4]); acc[5] = fmaf(b, a2, acc[5]);
        acc[6] = fmaf(b, a3, acc[6]); acc[7] = fmaf(b, a4, acc[7]);
        acc[8] = fmaf(g, db, acc[8]); acc[9] = fmaf(b, db, acc[9]);
    }
    #pragma unroll
    for (int v = 0; v < 10; v++) {
        float w = wsum(acc[v]);
        if (lane == 63) s_red[wave][v] = w;
    }
    __syncthreads();
    if (t < 10) ws[t] = s_red[0][t] + s_red[1][t] + s_red[2][t] + s_red[3][t];
}

__global__ __launch_bounds__(256) void hc_main(
    const float* __restrict__ h,     // (P, 4, 2048)
    const float* __restrict__ h_o,   // (P, 2048)
    const float* __restrict__ g_,    // (2048) ln_gamma
    const float* __restrict__ Bfn,   // (2048) dynamic_beta_fn
    const float* __restrict__ sA,    // (4, 5) static_alpha
    const float* __restrict__ sB,    // (4)    static_beta
    const float* __restrict__ ws,
    float* __restrict__ out)         // (P, 4, 2048)
{
    const int lane = threadIdx.x & 63;
    const int wv   = threadIdx.x >> 6;
    const size_t pos   = (size_t)blockIdx.x * 4 + wv;   // one position per wave
    const size_t pbase = pos * (size_t)(NRATE * NDIM);
    const int d0 = lane * 4;    // chunk c covers d = d0 + 256*c

    // uniform folded constants
    const float GA0 = ws[0], GA1 = ws[1], GA2 = ws[2], GA3 = ws[3];
    const float BA0 = ws[4], BA1 = ws[5], BA2 = ws[6], BA3 = ws[7];
    const float GB  = ws[8], BB  = ws[9];

    // ---- pass 1: stream h once, accumulate all 28 partials ----
    float S[NRATE]  = {0.f, 0.f, 0.f, 0.f};
    float SS[NRATE] = {0.f, 0.f, 0.f, 0.f};
    float Q[NRATE]  = {0.f, 0.f, 0.f, 0.f};
    float Pk[NRATE][4] = {};
    #pragma unroll 4
    for (int c = 0; c < 8; ++c) {
        const int d = d0 + 256 * c;
        const float4 g4 = *(const float4*)(g_ + d);
        const float4 q4 = *(const float4*)(Bfn + d);
        float4 a4[4];
        #pragma unroll
        for (int i = 0; i < 4; ++i) a4[i] = *(const float4*)(ws + WS_PK4 + 4 * (d + i));
        const float gs[4] = {g4.x, g4.y, g4.z, g4.w};
        const float qs[4] = {q4.x, q4.y, q4.z, q4.w};
        #pragma unroll
        for (int n = 0; n < NRATE; ++n) {
            const float4 x4 = *(const float4*)(h + pbase + n * NDIM + d);
            const float xs[4] = {x4.x, x4.y, x4.z, x4.w};
            #pragma unroll
            for (int i = 0; i < 4; ++i) {
                const float x = xs[i];
                S[n] += x;
                SS[n] = fmaf(x, x, SS[n]);
                const float xg = x * gs[i];
                Pk[n][0] = fmaf(xg, a4[i].x, Pk[n][0]);
                Pk[n][1] = fmaf(xg, a4[i].y, Pk[n][1]);
                Pk[n][2] = fmaf(xg, a4[i].z, Pk[n][2]);
                Pk[n][3] = fmaf(xg, a4[i].w, Pk[n][3]);
                Q[n]     = fmaf(xg, qs[i], Q[n]);
            }
        }
    }

    // ---- wave-internal reduce: DPP to lane 63, readlane-broadcast ----
    float red[28];
    #pragma unroll
    for (int n = 0; n < NRATE; n++) {
        red[n]     = S[n];
        red[4 + n] = SS[n];
        red[8 + n] = Q[n];
        #pragma unroll
        for (int k = 0; k < 4; k++) red[12 + n * 4 + k] = Pk[n][k];
    }
    float sums[28];
    #pragma unroll
    for (int v = 0; v < 28; v++) sums[v] = bcast63(wsum(red[v]));

    // ---- finalize alpha (cols 1..4) and beta (wave-uniform) ----
    float alpha_f[NRATE][4], beta_f[NRATE];
    #pragma unroll
    for (int n = 0; n < NRATE; n++) {
        const float m   = sums[n] * (1.0f / NDIM);
        const float var = sums[4 + n] * (1.0f / NDIM) - m * m;
        const float rs  = rsqrtf(var + LEPS);
        const float pk0 = sums[12 + n * 4 + 0], pk1 = sums[12 + n * 4 + 1];
        const float pk2 = sums[12 + n * 4 + 2], pk3 = sums[12 + n * 4 + 3];
        alpha_f[n][0] = fmaf(DSCALE, fmaf(rs, fmaf(-m, GA0, pk0), BA0), sA[n * 5 + 1]);
        alpha_f[n][1] = fmaf(DSCALE, fmaf(rs, fmaf(-m, GA1, pk1), BA1), sA[n * 5 + 2]);
        alpha_f[n][2] = fmaf(DSCALE, fmaf(rs, fmaf(-m, GA2, pk2), BA2), sA[n * 5 + 3]);
        alpha_f[n][3] = fmaf(DSCALE, fmaf(rs, fmaf(-m, GA3, pk3), BA3), sA[n * 5 + 4]);
        beta_f[n]     = fmaf(DSCALE, fmaf(rs, fmaf(-m, GB, sums[8 + n]), BB), sB[n]);
    }

    // ---- pass 2: re-stream h (L1/L2-hot) + h_o, write 4 output rows ----
    const float* hp  = h + pbase;
    const float* hop = h_o + pos * NDIM;
    float* op = out + pbase;
    #pragma unroll 4
    for (int c = 0; c < 8; ++c) {
        const int d = d0 + 256 * c;
        const float4 x0 = *(const float4*)(hp + 0 * NDIM + d);
        const float4 x1 = *(const float4*)(hp + 1 * NDIM + d);
        const float4 x2 = *(const float4*)(hp + 2 * NDIM + d);
        const float4 x3 = *(const float4*)(hp + 3 * NDIM + d);
        const float4 ho = *(const float4*)(hop + d);
        const float hs[4] = {ho.x, ho.y, ho.z, ho.w};
        const float xa[4][4] = {{x0.x, x0.y, x0.z, x0.w},
                                {x1.x, x1.y, x1.z, x1.w},
                                {x2.x, x2.y, x2.z, x2.w},
                                {x3.x, x3.y, x3.z, x3.w}};
        #pragma unroll
        for (int j = 0; j < NRATE; ++j) {
            vfloat4 o;
            #pragma unroll
            for (int i = 0; i < 4; ++i) {
                float acc = hs[i] * beta_f[j];
                #pragma unroll
                for (int n = 0; n < NRATE; ++n) acc = fmaf(alpha_f[n][j], xa[n][i], acc);
                o[i] = acc;
            }
            __builtin_nontemporal_store(o, (vfloat4*)(op + j * NDIM + d));
        }
    }
}

extern "C" void kernel_launch(void* const* d_in, const int* in_sizes, int n_in,
                              void* d_out, int out_size, void* d_ws, size_t ws_size,
                              hipStream_t stream) {
    const float* h   = (const float*)d_in[0];
    const float* h_o = (const float*)d_in[1];
    const float* g   = (const float*)d_in[2];
    const float* b   = (const float*)d_in[3];
    const float* A   = (const float*)d_in[4];
    const float* Bf  = (const float*)d_in[5];
    const float* sA  = (const float*)d_in[6];
    const float* sB  = (const float*)d_in[7];
    float* out = (float*)d_out;
    float* ws  = (float*)d_ws;   // ~33 KB used

    const int P = in_sizes[1] / NDIM;   // b*l = 8192
    hc_prep<<<1, 256, 0, stream>>>(g, b, A, Bf, ws);
    hc_main<<<P / 4, 256, 0, stream>>>(h, h_o, g, Bf, sA, sB, ws, out);
}